// Round 4
// baseline (562.013 us; speedup 1.0000x reference)
//
#include <hip/hip_runtime.h>
#include <hip/hip_bf16.h>

#define B_ 16
#define N_ 2000
#define E_ 8000
#define P_ 16000
#define XROW (E_ + N_)   // 10000 rows per batch in x
#define OROW (P_ + N_)   // 18000 rows per batch in out

typedef __hip_bfloat16 bf16;
typedef unsigned short u16;
typedef unsigned int u32;
typedef __attribute__((ext_vector_type(8))) short short8;   // 8 bf16 in 4 VGPRs
typedef __attribute__((ext_vector_type(4))) float f32x4;

__device__ __forceinline__ float b2f(bf16 v) { return __bfloat162float(v); }
__device__ __forceinline__ float u2f(u16 u) { return __uint_as_float(((u32)u) << 16); }
__device__ __forceinline__ float lo2f(u32 u) { return __uint_as_float(u << 16); }
__device__ __forceinline__ float hi2f(u32 u) { return __uint_as_float(u & 0xFFFF0000u); }
__device__ __forceinline__ u16 f2bu(float v) {
  bf16 b = __float2bfloat16(v);
  return *reinterpret_cast<u16*>(&b);
}

// dtype-agnostic input load
__device__ __forceinline__ float ldin(const void* p, int i, int f32) {
  return f32 ? ((const float*)p)[i] : __bfloat162float(((const bf16*)p)[i]);
}

// per-block dtype self-detect: view first 512B of x as bf16; f32 data
// shows ~70% wild/non-finite values in the low halves.
__device__ __forceinline__ int detect_f32(const void* x) {
  int lane = threadIdx.x & 63;
  ushort4 v = reinterpret_cast<const ushort4*>(x)[lane];
  int bad = 0;
  float f0 = u2f(v.x), f1 = u2f(v.y), f2 = u2f(v.z), f3 = u2f(v.w);
  if (!(fabsf(f0) < 1e4f)) bad++;
  if (!(fabsf(f1) < 1e4f)) bad++;
  if (!(fabsf(f2) < 1e4f)) bad++;
  if (!(fabsf(f3) < 1e4f)) bad++;
  unsigned long long m = __ballot(bad > 0);
  return __popcll(m) > 8;
}

// 8 consecutive input elems -> short8 of bf16 (A-fragment load)
__device__ __forceinline__ short8 ld8b(const void* p, size_t i, int f32) {
  short8 r;
  if (f32) {
    const float* f = (const float*)p + i;
    float4 v0 = *reinterpret_cast<const float4*>(f);
    float4 v1 = *reinterpret_cast<const float4*>(f + 4);
    u16* o = (u16*)&r;
    o[0] = f2bu(v0.x); o[1] = f2bu(v0.y); o[2] = f2bu(v0.z); o[3] = f2bu(v0.w);
    o[4] = f2bu(v1.x); o[5] = f2bu(v1.y); o[6] = f2bu(v1.z); o[7] = f2bu(v1.w);
  } else {
    r = *reinterpret_cast<const short8*>((const u16*)p + i);
  }
  return r;
}

// ---------- Kernel A: weight precompute (transposed bf16) + rowptr + cnt=0 ---
// Wtn[c][k] (192x64): c<64 -> W_node^T; c<128 -> (W_node@W1)^T; else (W_node@W3)^T
// Wte[c][k] (64x64): (W_edge@W2)^T.  c1 = b_node@W1, c3 = b_node@W3.
// rowptr[n] = lower_bound(src, n), n in [0,2000].
// cnt[b] = 0 (last-block counters for k_combine's fused smerge; ws is poisoned
// between iterations so zero-init MUST be in-graph, and k_pre precedes k_combine).
__global__ __launch_bounds__(256) void k_pre(
    const void* __restrict__ x,
    const void* __restrict__ W_edge, const void* __restrict__ W_node,
    const void* __restrict__ b_node, const void* __restrict__ W_comb,
    const int* __restrict__ src,
    u16* __restrict__ Wtn, u16* __restrict__ Wte,
    float* __restrict__ c1, float* __restrict__ c3,
    int* __restrict__ rowptr, int* __restrict__ cnt) {
  const int f32 = detect_f32(x);
  int o = blockIdx.x * 256 + threadIdx.x;
  if (o < 4096) {
    int c = o >> 6, k = o & 63;
    Wtn[c*64 + k] = f2bu(ldin(W_node, k*64 + c, f32));
  } else if (o < 12288) {
    int oo = o - 4096;            // [0, 8192)
    int cc = oo >> 6, k = oo & 63;
    int col = cc & 63;
    int base = (cc < 64) ? 0 : 128;
    float a = 0.f;
    for (int j = 0; j < 64; ++j)
      a += ldin(W_node, k*64 + j, f32) * ldin(W_comb, (base + j)*64 + col, f32);
    Wtn[(64 + cc)*64 + k] = f2bu(a);
  } else if (o < 16384) {
    int oo = o - 12288;
    int c = oo >> 6, k = oo & 63;
    float a = 0.f;
    for (int j = 0; j < 64; ++j)
      a += ldin(W_edge, k*64 + j, f32) * ldin(W_comb, (64 + j)*64 + c, f32);
    Wte[c*64 + k] = f2bu(a);
  } else if (o < 16448) {
    int j = o - 16384;
    float a = 0.f;
    for (int k = 0; k < 64; ++k) a += ldin(b_node, k, f32) * ldin(W_comb, k*64 + j, f32);
    c1[j] = a;
  } else if (o < 16512) {
    int j = o - 16448;
    float a = 0.f;
    for (int k = 0; k < 64; ++k) a += ldin(b_node, k, f32) * ldin(W_comb, (128 + k)*64 + j, f32);
    c3[j] = a;
  } else if (o < 16512 + N_ + 1) {
    int n = o - 16512;
    int lo = 0, hi = P_;
    while (lo < hi) { int mid = (lo + hi) >> 1; if (src[mid] < n) lo = mid + 1; else hi = mid; }
    rowptr[n] = lo;
  } else if (o < 16512 + N_ + 1 + B_) {
    cnt[o - (16512 + N_ + 1)] = 0;
  }
}

// ---------- Kernel B: fused node+edge transform, MFMA, LDS-free ----------
// blocks [0,500): node rows, 64/block (4 waves x 16 rows), 12 col-tiles:
//   [h|hs|hd](64x192) = X @ Wn(64x192)
// blocks [500,1500): edge rows, 128/block (4 waves x 32 rows), 4 col-tiles:
//   fe(128x64) = X @ A2
// A-frags straight from global x (coalesced: lanes {m,m+16,m+32,m+48} cover one
// row's 128B half); B-frags from precomputed transposed weights (L1-resident).
__global__ __launch_bounds__(256) void k_transform(
    const void* __restrict__ x,
    const u16* __restrict__ Wtn, const u16* __restrict__ Wte,
    const void* __restrict__ b_node,
    const float* __restrict__ c1, const float* __restrict__ c3,
    bf16* __restrict__ h, bf16* __restrict__ hs, bf16* __restrict__ hd,
    bf16* __restrict__ fe) {
  const int f32 = detect_f32(x);
  int t = threadIdx.x;
  int wave = t >> 6, lane = t & 63;
  int m16 = lane & 15, q = lane >> 4;
  if (blockIdx.x < 500) {
    int row0 = blockIdx.x * 64 + wave * 16;
    int arow = row0 + m16;
    int b = arow / N_, n = arow - b * N_;
    size_t xbase = (size_t)(b * XROW + E_ + n) * 64;
    short8 af0 = ld8b(x, xbase + q*8, f32);
    short8 af1 = ld8b(x, xbase + 32 + q*8, f32);
    f32x4 acc[12];
    #pragma unroll
    for (int c = 0; c < 12; ++c) acc[c] = (f32x4){0.f, 0.f, 0.f, 0.f};
    #pragma unroll
    for (int c = 0; c < 12; ++c) {
      short8 b0 = *reinterpret_cast<const short8*>(&Wtn[(c*16 + m16)*64 + q*8]);
      short8 b1 = *reinterpret_cast<const short8*>(&Wtn[(c*16 + m16)*64 + 32 + q*8]);
      acc[c] = __builtin_amdgcn_mfma_f32_16x16x32_bf16(af0, b0, acc[c], 0, 0, 0);
      acc[c] = __builtin_amdgcn_mfma_f32_16x16x32_bf16(af1, b1, acc[c], 0, 0, 0);
    }
    // D: col = m16 (within tile), row = q*4 + r
    #pragma unroll
    for (int c = 0; c < 12; ++c) {
      int seg = c >> 2;             // 0:h 1:hs 2:hd
      int lcol = (c*16 + m16) & 63;
      float bias = (seg == 0) ? ldin(b_node, lcol, f32) : (seg == 1 ? c1[lcol] : c3[lcol]);
      bf16* tgt = (seg == 0) ? h : (seg == 1 ? hs : hd);
      #pragma unroll
      for (int r = 0; r < 4; ++r) {
        int row = row0 + q*4 + r;
        tgt[(size_t)row*64 + lcol] = __float2bfloat16(acc[c][r] + bias);
      }
    }
  } else {
    int row0 = (blockIdx.x - 500) * 128 + wave * 32;
    short8 af[2][2];
    #pragma unroll
    for (int rt = 0; rt < 2; ++rt) {
      int arow = row0 + rt*16 + m16;
      int b = arow / E_, e = arow - b * E_;
      size_t xbase = (size_t)(b * XROW + e) * 64;
      af[rt][0] = ld8b(x, xbase + q*8, f32);
      af[rt][1] = ld8b(x, xbase + 32 + q*8, f32);
    }
    f32x4 acc[2][4];
    #pragma unroll
    for (int rt = 0; rt < 2; ++rt)
      #pragma unroll
      for (int c = 0; c < 4; ++c) acc[rt][c] = (f32x4){0.f, 0.f, 0.f, 0.f};
    #pragma unroll
    for (int c = 0; c < 4; ++c) {
      short8 b0 = *reinterpret_cast<const short8*>(&Wte[(c*16 + m16)*64 + q*8]);
      short8 b1 = *reinterpret_cast<const short8*>(&Wte[(c*16 + m16)*64 + 32 + q*8]);
      #pragma unroll
      for (int rt = 0; rt < 2; ++rt) {
        acc[rt][c] = __builtin_amdgcn_mfma_f32_16x16x32_bf16(af[rt][0], b0, acc[rt][c], 0, 0, 0);
        acc[rt][c] = __builtin_amdgcn_mfma_f32_16x16x32_bf16(af[rt][1], b1, acc[rt][c], 0, 0, 0);
      }
    }
    #pragma unroll
    for (int rt = 0; rt < 2; ++rt)
      #pragma unroll
      for (int c = 0; c < 4; ++c) {
        int col = c*16 + m16;
        #pragma unroll
        for (int r = 0; r < 4; ++r) {
          int row = row0 + rt*16 + q*4 + r;
          fe[(size_t)row*64 + col] = __float2bfloat16(acc[rt][c][r]);
        }
      }
  }
}

// ---------- Kernel C: gather+combine+lrelu+logit + softmax partial + fused
// last-block merge (k_smerge folded in via per-batch atomic counter) ----------
// 8 lanes/row x 8 ch (uint4 = 16B gathers), 32 rows/block (all same batch).
// XCD-chunk swizzle (T1): chunk = (bid&7)*1000 + bid>>3. mpart/spart indexed by
// CHUNK. After writing its partial, each block release-fences + atomicAdds
// cnt[batch]; the 500th block acquire-fences and runs the 500-way merge
// (bit-identical arithmetic to the old k_smerge) -> mb/sb.
__global__ __launch_bounds__(256) void k_combine(
    const void* __restrict__ x,
    const bf16* __restrict__ hs, const bf16* __restrict__ hd,
    const bf16* __restrict__ fe, const void* __restrict__ b_comb,
    const void* __restrict__ w_attn,
    const int* __restrict__ src, const int* __restrict__ dst,
    const int* __restrict__ eidx,
    void* __restrict__ out, float* __restrict__ logits,
    float* __restrict__ mpart, float* __restrict__ spart,
    int* __restrict__ cnt, float* __restrict__ mb, float* __restrict__ sb) {
  const int f32 = detect_f32(x);
  __shared__ float bias[64], watt[64];
  __shared__ float ld_log[32];
  __shared__ float rm[256], rs[256];
  __shared__ int is_last;
  int t = threadIdx.x;
  if (t < 64) { bias[t] = ldin(b_comb, t, f32); watt[t] = ldin(w_attn, t, f32); }
  __syncthreads();
  int chunk = (blockIdx.x & 7) * 1000 + (blockIdx.x >> 3);  // bijective, 8000%8==0
  int lane = t & 63, wave = t >> 6;
  int grp = lane >> 3, sub = lane & 7, c0 = sub * 8;
  int r = chunk * 32 + wave * 8 + grp;   // [0, B*P)
  int b = r / P_, p = r - b * P_;
  int s = src[p], d2 = dst[p], e = eidx[p];
  uint4 ua = *reinterpret_cast<const uint4*>((const u16*)hs + (size_t)(b*N_ + s)*64 + c0);
  uint4 uf = *reinterpret_cast<const uint4*>((const u16*)fe + (size_t)(b*E_ + e)*64 + c0);
  uint4 ud = *reinterpret_cast<const uint4*>((const u16*)hd + (size_t)(b*N_ + d2)*64 + c0);
  float v[8];
  v[0] = lo2f(ua.x) + lo2f(uf.x) + lo2f(ud.x) + bias[c0+0];
  v[1] = hi2f(ua.x) + hi2f(uf.x) + hi2f(ud.x) + bias[c0+1];
  v[2] = lo2f(ua.y) + lo2f(uf.y) + lo2f(ud.y) + bias[c0+2];
  v[3] = hi2f(ua.y) + hi2f(uf.y) + hi2f(ud.y) + bias[c0+3];
  v[4] = lo2f(ua.z) + lo2f(uf.z) + lo2f(ud.z) + bias[c0+4];
  v[5] = hi2f(ua.z) + hi2f(uf.z) + hi2f(ud.z) + bias[c0+5];
  v[6] = lo2f(ua.w) + lo2f(uf.w) + lo2f(ud.w) + bias[c0+6];
  v[7] = hi2f(ua.w) + hi2f(uf.w) + hi2f(ud.w) + bias[c0+7];
  float l = 0.f;
  #pragma unroll
  for (int j = 0; j < 8; ++j) {
    v[j] = v[j] > 0.f ? v[j] : 0.01f * v[j];
    l += v[j] * watt[c0 + j];
  }
  size_t obase = (size_t)(b*OROW + p)*64 + c0;
  if (f32) {
    float4 o0; o0.x = v[0]; o0.y = v[1]; o0.z = v[2]; o0.w = v[3];
    float4 o1; o1.x = v[4]; o1.y = v[5]; o1.z = v[6]; o1.w = v[7];
    *reinterpret_cast<float4*>((float*)out + obase)     = o0;
    *reinterpret_cast<float4*>((float*)out + obase + 4) = o1;
  } else {
    uint4 o;
    o.x = ((u32)f2bu(v[1]) << 16) | f2bu(v[0]);
    o.y = ((u32)f2bu(v[3]) << 16) | f2bu(v[2]);
    o.z = ((u32)f2bu(v[5]) << 16) | f2bu(v[4]);
    o.w = ((u32)f2bu(v[7]) << 16) | f2bu(v[6]);
    *reinterpret_cast<uint4*>((u16*)out + obase) = o;
  }
  l += __shfl_down(l, 4, 8);
  l += __shfl_down(l, 2, 8);
  l += __shfl_down(l, 1, 8);
  if (sub == 0) {
    logits[b*P_ + p] = l;
    ld_log[wave * 8 + grp] = l;
  }
  __syncthreads();
  if (t < 32) {
    float li = ld_log[t];
    float m = li;
    #pragma unroll
    for (int o = 16; o > 0; o >>= 1) m = fmaxf(m, __shfl_xor(m, o, 32));
    float sv = __expf(li - m);
    #pragma unroll
    for (int o = 16; o > 0; o >>= 1) sv += __shfl_xor(sv, o, 32);
    if (t == 0) {
      mpart[chunk] = m; spart[chunk] = sv;
      __threadfence();                       // release partial before count
      int prev = atomicAdd(&cnt[chunk / 500], 1);
      is_last = (prev == 499);
    }
  }
  __syncthreads();
  if (is_last) {
    __threadfence();                         // acquire all partials
    int bb = chunk / 500;
    float m = -1e30f, s = 0.f;
    for (int j = t; j < 500; j += 256) {
      float mj = mpart[500*bb + j], sj = spart[500*bb + j];
      float nm = fmaxf(m, mj);
      s = s * __expf(m - nm) + sj * __expf(mj - nm);
      m = nm;
    }
    rm[t] = m; rs[t] = s; __syncthreads();
    for (int st = 128; st > 0; st >>= 1) {
      if (t < st) {
        float mo = rm[t + st], so = rs[t + st];
        float nm = fmaxf(rm[t], mo);
        rs[t] = rs[t] * __expf(rm[t] - nm) + so * __expf(mo - nm);
        rm[t] = nm;
      }
      __syncthreads();
    }
    if (t == 0) { mb[bb] = rm[0]; sb[bb] = 1.0f / rs[0]; }
  }
}

// ---------- Kernel D: h_out ----------
// grid (N_, 4), block 256 = 4 waves (one batch each). rowptr gives the node's
// edge range; 4 edge-groups x 16 ch gather-dot; xor-reduce across groups.
__global__ __launch_bounds__(256) void k_hout(
    const void* __restrict__ x,
    const bf16* __restrict__ h, const float* __restrict__ logits,
    const float* __restrict__ mb, const float* __restrict__ sb,
    const int* __restrict__ rowptr, const int* __restrict__ dst,
    void* __restrict__ out) {
  const int f32 = detect_f32(x);
  int n = blockIdx.x;
  int t = threadIdx.x;
  int wave = t >> 6, lane = t & 63;
  int b = blockIdx.y * 4 + wave;
  float m = mb[b], inv = sb[b];
  int start = rowptr[n], end = rowptr[n + 1];
  int grp = lane >> 4, sub = lane & 15, c0 = sub * 4;
  float a0 = 0.f, a1 = 0.f, a2 = 0.f, a3 = 0.f;
  for (int p = start + grp; p < end; p += 4) {
    float a = __expf(logits[b*P_ + p] - m) * inv;
    int dn = dst[p];
    ushort4 hv = *reinterpret_cast<const ushort4*>((const u16*)h + (size_t)(b*N_ + dn)*64 + c0);
    a0 += a * u2f(hv.x); a1 += a * u2f(hv.y);
    a2 += a * u2f(hv.z); a3 += a * u2f(hv.w);
  }
  a0 += __shfl_xor(a0, 16, 64); a0 += __shfl_xor(a0, 32, 64);
  a1 += __shfl_xor(a1, 16, 64); a1 += __shfl_xor(a1, 32, 64);
  a2 += __shfl_xor(a2, 16, 64); a2 += __shfl_xor(a2, 32, 64);
  a3 += __shfl_xor(a3, 16, 64); a3 += __shfl_xor(a3, 32, 64);
  if (grp == 0) {
    size_t obase = (size_t)(b*OROW + P_ + n)*64 + c0;
    if (f32) {
      float4 o4; o4.x = a0; o4.y = a1; o4.z = a2; o4.w = a3;
      *reinterpret_cast<float4*>((float*)out + obase) = o4;
    } else {
      ushort4 o4;
      o4.x = f2bu(a0); o4.y = f2bu(a1); o4.z = f2bu(a2); o4.w = f2bu(a3);
      *reinterpret_cast<ushort4*>((u16*)out + obase) = o4;
    }
  }
}

extern "C" void kernel_launch(void* const* d_in, const int* in_sizes, int n_in,
                              void* d_out, int out_size, void* d_ws, size_t ws_size,
                              hipStream_t stream) {
  const void* x      = d_in[0];
  const void* W_edge = d_in[1];
  const void* W_node = d_in[2];
  const void* b_node = d_in[3];
  const void* W_comb = d_in[4];
  const void* b_comb = d_in[5];
  const void* w_attn = d_in[6];
  const int* src  = (const int*)d_in[7];
  const int* dst  = (const int*)d_in[8];
  const int* eidx = (const int*)d_in[9];

  // workspace layout (f32 units)
  float* logits = (float*)d_ws;          // 256000
  float* mpart  = logits + B_*P_;        // 8000
  float* spart  = mpart + 8000;          // 8000
  float* mb     = spart + 8000;          // 16
  float* sb     = mb + B_;               // 16
  float* c1     = sb + B_;               // 64
  float* c3     = c1 + 64;               // 64
  int*   rowptr = (int*)(c3 + 64);       // 2016 (padded)
  int*   cnt    = rowptr + 2016;         // 16 (last-block counters)
  u16*   Wtn    = (u16*)(cnt + 16);      // 192*64
  u16*   Wte    = Wtn + 192*64;          // 64*64
  bf16*  h      = (bf16*)(Wte + 64*64);  // B*N*64
  bf16*  hs     = h  + B_*N_*64;
  bf16*  hd     = hs + B_*N_*64;
  bf16*  fe     = hd + B_*N_*64;         // B*E*64

  k_pre<<<73, 256, 0, stream>>>(x, W_edge, W_node, b_node, W_comb, src, Wtn, Wte, c1, c3, rowptr, cnt);
  k_transform<<<1500, 256, 0, stream>>>(x, Wtn, Wte, b_node, c1, c3, h, hs, hd, fe);
  k_combine<<<(B_*P_)/32, 256, 0, stream>>>(x, hs, hd, fe, b_comb, w_attn, src, dst, eidx, d_out, logits, mpart, spart, cnt, mb, sb);
  k_hout<<<dim3(N_, B_/4), 256, 0, stream>>>(x, h, logits, mb, sb, rowptr, dst, d_out);
}

// Round 5
// 177.019 us; speedup vs baseline: 3.1749x; 3.1749x over previous
//
#include <hip/hip_runtime.h>
#include <hip/hip_bf16.h>

#define B_ 16
#define N_ 2000
#define E_ 8000
#define P_ 16000
#define XROW (E_ + N_)   // 10000 rows per batch in x
#define OROW (P_ + N_)   // 18000 rows per batch in out

typedef __hip_bfloat16 bf16;
typedef unsigned short u16;
typedef unsigned int u32;
typedef __attribute__((ext_vector_type(8))) short short8;   // 8 bf16 in 4 VGPRs
typedef __attribute__((ext_vector_type(4))) float f32x4;

__device__ __forceinline__ float b2f(bf16 v) { return __bfloat162float(v); }
__device__ __forceinline__ float u2f(u16 u) { return __uint_as_float(((u32)u) << 16); }
__device__ __forceinline__ float lo2f(u32 u) { return __uint_as_float(u << 16); }
__device__ __forceinline__ float hi2f(u32 u) { return __uint_as_float(u & 0xFFFF0000u); }
__device__ __forceinline__ u16 f2bu(float v) {
  bf16 b = __float2bfloat16(v);
  return *reinterpret_cast<u16*>(&b);
}

// dtype-agnostic input load
__device__ __forceinline__ float ldin(const void* p, int i, int f32) {
  return f32 ? ((const float*)p)[i] : __bfloat162float(((const bf16*)p)[i]);
}

// dtype self-detect: view first 512B of x as bf16; f32 data shows ~70%
// wild/non-finite values in the low halves. Run ONCE in k_pre, result stored
// to ws (flags[0]); other kernels do a single uniform scalar load instead of
// a 512B read + ballot chain at the head of every block (R4 post-mortem:
// k_combine is latency-bound, block prologue is on the critical path).
__device__ __forceinline__ int detect_f32(const void* x) {
  int lane = threadIdx.x & 63;
  ushort4 v = reinterpret_cast<const ushort4*>(x)[lane];
  int bad = 0;
  float f0 = u2f(v.x), f1 = u2f(v.y), f2 = u2f(v.z), f3 = u2f(v.w);
  if (!(fabsf(f0) < 1e4f)) bad++;
  if (!(fabsf(f1) < 1e4f)) bad++;
  if (!(fabsf(f2) < 1e4f)) bad++;
  if (!(fabsf(f3) < 1e4f)) bad++;
  unsigned long long m = __ballot(bad > 0);
  return __popcll(m) > 8;
}

// 8 consecutive input elems -> short8 of bf16 (A-fragment load)
__device__ __forceinline__ short8 ld8b(const void* p, size_t i, int f32) {
  short8 r;
  if (f32) {
    const float* f = (const float*)p + i;
    float4 v0 = *reinterpret_cast<const float4*>(f);
    float4 v1 = *reinterpret_cast<const float4*>(f + 4);
    u16* o = (u16*)&r;
    o[0] = f2bu(v0.x); o[1] = f2bu(v0.y); o[2] = f2bu(v0.z); o[3] = f2bu(v0.w);
    o[4] = f2bu(v1.x); o[5] = f2bu(v1.y); o[6] = f2bu(v1.z); o[7] = f2bu(v1.w);
  } else {
    r = *reinterpret_cast<const short8*>((const u16*)p + i);
  }
  return r;
}

// ---------- Kernel A: weight precompute (transposed bf16) + rowptr + flag ----
// Wtn[c][k] (192x64): c<64 -> W_node^T; c<128 -> (W_node@W1)^T; else (W_node@W3)^T
// Wte[c][k] (64x64): (W_edge@W2)^T.  c1 = b_node@W1, c3 = b_node@W3.
// rowptr[n] = lower_bound(src, n), n in [0,2000].  flags[0] = f32 dtype flag.
__global__ __launch_bounds__(256) void k_pre(
    const void* __restrict__ x,
    const void* __restrict__ W_edge, const void* __restrict__ W_node,
    const void* __restrict__ b_node, const void* __restrict__ W_comb,
    const int* __restrict__ src,
    u16* __restrict__ Wtn, u16* __restrict__ Wte,
    float* __restrict__ c1, float* __restrict__ c3,
    int* __restrict__ rowptr, int* __restrict__ flags) {
  const int f32 = detect_f32(x);
  int o = blockIdx.x * 256 + threadIdx.x;
  if (o < 4096) {
    int c = o >> 6, k = o & 63;
    Wtn[c*64 + k] = f2bu(ldin(W_node, k*64 + c, f32));
  } else if (o < 12288) {
    int oo = o - 4096;            // [0, 8192)
    int cc = oo >> 6, k = oo & 63;
    int col = cc & 63;
    int base = (cc < 64) ? 0 : 128;
    float a = 0.f;
    for (int j = 0; j < 64; ++j)
      a += ldin(W_node, k*64 + j, f32) * ldin(W_comb, (base + j)*64 + col, f32);
    Wtn[(64 + cc)*64 + k] = f2bu(a);
  } else if (o < 16384) {
    int oo = o - 12288;
    int c = oo >> 6, k = oo & 63;
    float a = 0.f;
    for (int j = 0; j < 64; ++j)
      a += ldin(W_edge, k*64 + j, f32) * ldin(W_comb, (64 + j)*64 + c, f32);
    Wte[c*64 + k] = f2bu(a);
  } else if (o < 16448) {
    int j = o - 16384;
    float a = 0.f;
    for (int k = 0; k < 64; ++k) a += ldin(b_node, k, f32) * ldin(W_comb, k*64 + j, f32);
    c1[j] = a;
  } else if (o < 16512) {
    int j = o - 16448;
    float a = 0.f;
    for (int k = 0; k < 64; ++k) a += ldin(b_node, k, f32) * ldin(W_comb, (128 + k)*64 + j, f32);
    c3[j] = a;
  } else if (o < 16512 + N_ + 1) {
    int n = o - 16512;
    int lo = 0, hi = P_;
    while (lo < hi) { int mid = (lo + hi) >> 1; if (src[mid] < n) lo = mid + 1; else hi = mid; }
    rowptr[n] = lo;
  } else if (o == 16512 + N_ + 1) {
    flags[0] = f32;
  }
}

// ---------- Kernel B: fused node+edge transform, MFMA, LDS-free ----------
// blocks [0,500): node rows, 64/block (4 waves x 16 rows), 12 col-tiles:
//   [h|hs|hd](64x192) = X @ Wn(64x192)
// blocks [500,1500): edge rows, 128/block (4 waves x 32 rows), 4 col-tiles:
//   fe(128x64) = X @ A2
// A-frags straight from global x (coalesced: lanes {m,m+16,m+32,m+48} cover one
// row's 128B half); B-frags from precomputed transposed weights (L1-resident).
__global__ __launch_bounds__(256) void k_transform(
    const void* __restrict__ x, const int* __restrict__ flags,
    const u16* __restrict__ Wtn, const u16* __restrict__ Wte,
    const void* __restrict__ b_node,
    const float* __restrict__ c1, const float* __restrict__ c3,
    bf16* __restrict__ h, bf16* __restrict__ hs, bf16* __restrict__ hd,
    bf16* __restrict__ fe) {
  const int f32 = flags[0];
  int t = threadIdx.x;
  int wave = t >> 6, lane = t & 63;
  int m16 = lane & 15, q = lane >> 4;
  if (blockIdx.x < 500) {
    int row0 = blockIdx.x * 64 + wave * 16;
    int arow = row0 + m16;
    int b = arow / N_, n = arow - b * N_;
    size_t xbase = (size_t)(b * XROW + E_ + n) * 64;
    short8 af0 = ld8b(x, xbase + q*8, f32);
    short8 af1 = ld8b(x, xbase + 32 + q*8, f32);
    f32x4 acc[12];
    #pragma unroll
    for (int c = 0; c < 12; ++c) acc[c] = (f32x4){0.f, 0.f, 0.f, 0.f};
    #pragma unroll
    for (int c = 0; c < 12; ++c) {
      short8 b0 = *reinterpret_cast<const short8*>(&Wtn[(c*16 + m16)*64 + q*8]);
      short8 b1 = *reinterpret_cast<const short8*>(&Wtn[(c*16 + m16)*64 + 32 + q*8]);
      acc[c] = __builtin_amdgcn_mfma_f32_16x16x32_bf16(af0, b0, acc[c], 0, 0, 0);
      acc[c] = __builtin_amdgcn_mfma_f32_16x16x32_bf16(af1, b1, acc[c], 0, 0, 0);
    }
    // D: col = m16 (within tile), row = q*4 + r
    #pragma unroll
    for (int c = 0; c < 12; ++c) {
      int seg = c >> 2;             // 0:h 1:hs 2:hd
      int lcol = (c*16 + m16) & 63;
      float bias = (seg == 0) ? ldin(b_node, lcol, f32) : (seg == 1 ? c1[lcol] : c3[lcol]);
      bf16* tgt = (seg == 0) ? h : (seg == 1 ? hs : hd);
      #pragma unroll
      for (int r = 0; r < 4; ++r) {
        int row = row0 + q*4 + r;
        tgt[(size_t)row*64 + lcol] = __float2bfloat16(acc[c][r] + bias);
      }
    }
  } else {
    int row0 = (blockIdx.x - 500) * 128 + wave * 32;
    short8 af[2][2];
    #pragma unroll
    for (int rt = 0; rt < 2; ++rt) {
      int arow = row0 + rt*16 + m16;
      int b = arow / E_, e = arow - b * E_;
      size_t xbase = (size_t)(b * XROW + e) * 64;
      af[rt][0] = ld8b(x, xbase + q*8, f32);
      af[rt][1] = ld8b(x, xbase + 32 + q*8, f32);
    }
    f32x4 acc[2][4];
    #pragma unroll
    for (int rt = 0; rt < 2; ++rt)
      #pragma unroll
      for (int c = 0; c < 4; ++c) acc[rt][c] = (f32x4){0.f, 0.f, 0.f, 0.f};
    #pragma unroll
    for (int c = 0; c < 4; ++c) {
      short8 b0 = *reinterpret_cast<const short8*>(&Wte[(c*16 + m16)*64 + q*8]);
      short8 b1 = *reinterpret_cast<const short8*>(&Wte[(c*16 + m16)*64 + 32 + q*8]);
      #pragma unroll
      for (int rt = 0; rt < 2; ++rt) {
        acc[rt][c] = __builtin_amdgcn_mfma_f32_16x16x32_bf16(af[rt][0], b0, acc[rt][c], 0, 0, 0);
        acc[rt][c] = __builtin_amdgcn_mfma_f32_16x16x32_bf16(af[rt][1], b1, acc[rt][c], 0, 0, 0);
      }
    }
    #pragma unroll
    for (int rt = 0; rt < 2; ++rt)
      #pragma unroll
      for (int c = 0; c < 4; ++c) {
        int col = c*16 + m16;
        #pragma unroll
        for (int r = 0; r < 4; ++r) {
          int row = row0 + rt*16 + q*4 + r;
          fe[(size_t)row*64 + col] = __float2bfloat16(acc[rt][c][r]);
        }
      }
  }
}

// ---------- Kernel C: gather+combine+lrelu+logit + per-block softmax partial --
// 8 lanes/row x 8 ch (uint4 = 16B gathers), 32 rows/block (all same batch).
// XCD-chunk swizzle (T1): chunk = (bid&7)*1000 + bid>>3. mpart/spart indexed by
// CHUNK (batch b partials = chunks [500b, 500b+500), matching k_smerge).
__global__ __launch_bounds__(256) void k_combine(
    const int* __restrict__ flags,
    const bf16* __restrict__ hs, const bf16* __restrict__ hd,
    const bf16* __restrict__ fe, const void* __restrict__ b_comb,
    const void* __restrict__ w_attn,
    const int* __restrict__ src, const int* __restrict__ dst,
    const int* __restrict__ eidx,
    void* __restrict__ out, float* __restrict__ logits,
    float* __restrict__ mpart, float* __restrict__ spart) {
  const int f32 = flags[0];
  __shared__ float bias[64], watt[64];
  __shared__ float ld_log[32];
  int t = threadIdx.x;
  if (t < 64) { bias[t] = ldin(b_comb, t, f32); watt[t] = ldin(w_attn, t, f32); }
  __syncthreads();
  int chunk = (blockIdx.x & 7) * 1000 + (blockIdx.x >> 3);  // bijective, 8000%8==0
  int lane = t & 63, wave = t >> 6;
  int grp = lane >> 3, sub = lane & 7, c0 = sub * 8;
  int r = chunk * 32 + wave * 8 + grp;   // [0, B*P)
  int b = r / P_, p = r - b * P_;
  int s = src[p], d2 = dst[p], e = eidx[p];
  uint4 ua = *reinterpret_cast<const uint4*>((const u16*)hs + (size_t)(b*N_ + s)*64 + c0);
  uint4 uf = *reinterpret_cast<const uint4*>((const u16*)fe + (size_t)(b*E_ + e)*64 + c0);
  uint4 ud = *reinterpret_cast<const uint4*>((const u16*)hd + (size_t)(b*N_ + d2)*64 + c0);
  float v[8];
  v[0] = lo2f(ua.x) + lo2f(uf.x) + lo2f(ud.x) + bias[c0+0];
  v[1] = hi2f(ua.x) + hi2f(uf.x) + hi2f(ud.x) + bias[c0+1];
  v[2] = lo2f(ua.y) + lo2f(uf.y) + lo2f(ud.y) + bias[c0+2];
  v[3] = hi2f(ua.y) + hi2f(uf.y) + hi2f(ud.y) + bias[c0+3];
  v[4] = lo2f(ua.z) + lo2f(uf.z) + lo2f(ud.z) + bias[c0+4];
  v[5] = hi2f(ua.z) + hi2f(uf.z) + hi2f(ud.z) + bias[c0+5];
  v[6] = lo2f(ua.w) + lo2f(uf.w) + lo2f(ud.w) + bias[c0+6];
  v[7] = hi2f(ua.w) + hi2f(uf.w) + hi2f(ud.w) + bias[c0+7];
  float l = 0.f;
  #pragma unroll
  for (int j = 0; j < 8; ++j) {
    v[j] = v[j] > 0.f ? v[j] : 0.01f * v[j];
    l += v[j] * watt[c0 + j];
  }
  size_t obase = (size_t)(b*OROW + p)*64 + c0;
  if (f32) {
    float4 o0; o0.x = v[0]; o0.y = v[1]; o0.z = v[2]; o0.w = v[3];
    float4 o1; o1.x = v[4]; o1.y = v[5]; o1.z = v[6]; o1.w = v[7];
    *reinterpret_cast<float4*>((float*)out + obase)     = o0;
    *reinterpret_cast<float4*>((float*)out + obase + 4) = o1;
  } else {
    uint4 o;
    o.x = ((u32)f2bu(v[1]) << 16) | f2bu(v[0]);
    o.y = ((u32)f2bu(v[3]) << 16) | f2bu(v[2]);
    o.z = ((u32)f2bu(v[5]) << 16) | f2bu(v[4]);
    o.w = ((u32)f2bu(v[7]) << 16) | f2bu(v[6]);
    *reinterpret_cast<uint4*>((u16*)out + obase) = o;
  }
  l += __shfl_down(l, 4, 8);
  l += __shfl_down(l, 2, 8);
  l += __shfl_down(l, 1, 8);
  if (sub == 0) {
    logits[b*P_ + p] = l;
    ld_log[wave * 8 + grp] = l;
  }
  __syncthreads();
  if (t < 32) {
    float li = ld_log[t];
    float m = li;
    #pragma unroll
    for (int o = 16; o > 0; o >>= 1) m = fmaxf(m, __shfl_xor(m, o, 32));
    float sv = __expf(li - m);
    #pragma unroll
    for (int o = 16; o > 0; o >>= 1) sv += __shfl_xor(sv, o, 32);
    if (t == 0) { mpart[chunk] = m; spart[chunk] = sv; }
  }
}

// ---------- Kernel C2: merge 500 partials per batch -> (M, 1/S) ----------
__global__ __launch_bounds__(256) void k_smerge(
    const float* __restrict__ mpart, const float* __restrict__ spart,
    float* __restrict__ mb, float* __restrict__ sb) {
  __shared__ float rm[256], rs[256];
  int b = blockIdx.x, t = threadIdx.x;
  float m = -1e30f, s = 0.f;
  for (int j = t; j < 500; j += 256) {
    float mj = mpart[500*b + j], sj = spart[500*b + j];
    float nm = fmaxf(m, mj);
    s = s * __expf(m - nm) + sj * __expf(mj - nm);
    m = nm;
  }
  rm[t] = m; rs[t] = s; __syncthreads();
  for (int st = 128; st > 0; st >>= 1) {
    if (t < st) {
      float mo = rm[t + st], so = rs[t + st];
      float nm = fmaxf(rm[t], mo);
      rs[t] = rs[t] * __expf(rm[t] - nm) + so * __expf(mo - nm);
      rm[t] = nm;
    }
    __syncthreads();
  }
  if (t == 0) { mb[b] = rm[0]; sb[b] = 1.0f / rs[0]; }
}

// ---------- Kernel D: h_out ----------
// grid (N_, 4), block 256 = 4 waves (one batch each). rowptr gives the node's
// edge range; 4 edge-groups x 16 ch gather-dot; xor-reduce across groups.
__global__ __launch_bounds__(256) void k_hout(
    const int* __restrict__ flags,
    const bf16* __restrict__ h, const float* __restrict__ logits,
    const float* __restrict__ mb, const float* __restrict__ sb,
    const int* __restrict__ rowptr, const int* __restrict__ dst,
    void* __restrict__ out) {
  const int f32 = flags[0];
  int n = blockIdx.x;
  int t = threadIdx.x;
  int wave = t >> 6, lane = t & 63;
  int b = blockIdx.y * 4 + wave;
  float m = mb[b], inv = sb[b];
  int start = rowptr[n], end = rowptr[n + 1];
  int grp = lane >> 4, sub = lane & 15, c0 = sub * 4;
  float a0 = 0.f, a1 = 0.f, a2 = 0.f, a3 = 0.f;
  for (int p = start + grp; p < end; p += 4) {
    float a = __expf(logits[b*P_ + p] - m) * inv;
    int dn = dst[p];
    ushort4 hv = *reinterpret_cast<const ushort4*>((const u16*)h + (size_t)(b*N_ + dn)*64 + c0);
    a0 += a * u2f(hv.x); a1 += a * u2f(hv.y);
    a2 += a * u2f(hv.z); a3 += a * u2f(hv.w);
  }
  a0 += __shfl_xor(a0, 16, 64); a0 += __shfl_xor(a0, 32, 64);
  a1 += __shfl_xor(a1, 16, 64); a1 += __shfl_xor(a1, 32, 64);
  a2 += __shfl_xor(a2, 16, 64); a2 += __shfl_xor(a2, 32, 64);
  a3 += __shfl_xor(a3, 16, 64); a3 += __shfl_xor(a3, 32, 64);
  if (grp == 0) {
    size_t obase = (size_t)(b*OROW + P_ + n)*64 + c0;
    if (f32) {
      float4 o4; o4.x = a0; o4.y = a1; o4.z = a2; o4.w = a3;
      *reinterpret_cast<float4*>((float*)out + obase) = o4;
    } else {
      ushort4 o4;
      o4.x = f2bu(a0); o4.y = f2bu(a1); o4.z = f2bu(a2); o4.w = f2bu(a3);
      *reinterpret_cast<ushort4*>((u16*)out + obase) = o4;
    }
  }
}

extern "C" void kernel_launch(void* const* d_in, const int* in_sizes, int n_in,
                              void* d_out, int out_size, void* d_ws, size_t ws_size,
                              hipStream_t stream) {
  const void* x      = d_in[0];
  const void* W_edge = d_in[1];
  const void* W_node = d_in[2];
  const void* b_node = d_in[3];
  const void* W_comb = d_in[4];
  const void* b_comb = d_in[5];
  const void* w_attn = d_in[6];
  const int* src  = (const int*)d_in[7];
  const int* dst  = (const int*)d_in[8];
  const int* eidx = (const int*)d_in[9];

  // workspace layout (f32 units)
  float* logits = (float*)d_ws;          // 256000
  float* mpart  = logits + B_*P_;        // 8000
  float* spart  = mpart + 8000;          // 8000
  float* mb     = spart + 8000;          // 16
  float* sb     = mb + B_;               // 16
  float* c1     = sb + B_;               // 64
  float* c3     = c1 + 64;               // 64
  int*   rowptr = (int*)(c3 + 64);       // 2016 (padded)
  int*   flags  = rowptr + 2016;         // 16 (dtype flag, padded)
  u16*   Wtn    = (u16*)(flags + 16);    // 192*64
  u16*   Wte    = Wtn + 192*64;          // 64*64
  bf16*  h      = (bf16*)(Wte + 64*64);  // B*N*64
  bf16*  hs     = h  + B_*N_*64;
  bf16*  hd     = hs + B_*N_*64;
  bf16*  fe     = hd + B_*N_*64;         // B*E*64

  k_pre<<<73, 256, 0, stream>>>(x, W_edge, W_node, b_node, W_comb, src, Wtn, Wte, c1, c3, rowptr, flags);
  k_transform<<<1500, 256, 0, stream>>>(x, flags, Wtn, Wte, b_node, c1, c3, h, hs, hd, fe);
  k_combine<<<(B_*P_)/32, 256, 0, stream>>>(flags, hs, hd, fe, b_comb, w_attn, src, dst, eidx, d_out, logits, mpart, spart);
  k_smerge<<<B_, 256, 0, stream>>>(mpart, spart, mb, sb);
  k_hout<<<dim3(N_, B_/4), 256, 0, stream>>>(flags, h, logits, mb, sb, rowptr, dst, d_out);
}

// Round 8
// 175.527 us; speedup vs baseline: 3.2019x; 1.0085x over previous
//
#include <hip/hip_runtime.h>
#include <hip/hip_bf16.h>

#define B_ 16
#define N_ 2000
#define E_ 8000
#define P_ 16000
#define XROW (E_ + N_)   // 10000 rows per batch in x
#define OROW (P_ + N_)   // 18000 rows per batch in out

typedef __hip_bfloat16 bf16;
typedef unsigned short u16;
typedef unsigned int u32;
typedef __attribute__((ext_vector_type(8))) short short8;   // 8 bf16 in 4 VGPRs
typedef __attribute__((ext_vector_type(4))) float f32x4;
typedef __attribute__((ext_vector_type(4))) unsigned int u32x4;    // nt-store-able
typedef __attribute__((ext_vector_type(4))) unsigned short u16x4;  // nt-store-able

__device__ __forceinline__ float b2f(bf16 v) { return __bfloat162float(v); }
__device__ __forceinline__ float u2f(u16 u) { return __uint_as_float(((u32)u) << 16); }
__device__ __forceinline__ float lo2f(u32 u) { return __uint_as_float(u << 16); }
__device__ __forceinline__ float hi2f(u32 u) { return __uint_as_float(u & 0xFFFF0000u); }
__device__ __forceinline__ u16 f2bu(float v) {
  bf16 b = __float2bfloat16(v);
  return *reinterpret_cast<u16*>(&b);
}

// dtype-agnostic input load
__device__ __forceinline__ float ldin(const void* p, int i, int f32) {
  return f32 ? ((const float*)p)[i] : __bfloat162float(((const bf16*)p)[i]);
}

// dtype self-detect: view first 512B of x as bf16; f32 data shows ~70%
// wild/non-finite values in the low halves. Run ONCE in k_pre (R5: hoisting
// out of the per-block prologue was worth ~1.4 µs).
__device__ __forceinline__ int detect_f32(const void* x) {
  int lane = threadIdx.x & 63;
  ushort4 v = reinterpret_cast<const ushort4*>(x)[lane];
  int bad = 0;
  float f0 = u2f(v.x), f1 = u2f(v.y), f2 = u2f(v.z), f3 = u2f(v.w);
  if (!(fabsf(f0) < 1e4f)) bad++;
  if (!(fabsf(f1) < 1e4f)) bad++;
  if (!(fabsf(f2) < 1e4f)) bad++;
  if (!(fabsf(f3) < 1e4f)) bad++;
  unsigned long long m = __ballot(bad > 0);
  return __popcll(m) > 8;
}

// 8 consecutive input elems -> short8 of bf16 (A-fragment load)
__device__ __forceinline__ short8 ld8b(const void* p, size_t i, int f32) {
  short8 r;
  if (f32) {
    const float* f = (const float*)p + i;
    float4 v0 = *reinterpret_cast<const float4*>(f);
    float4 v1 = *reinterpret_cast<const float4*>(f + 4);
    u16* o = (u16*)&r;
    o[0] = f2bu(v0.x); o[1] = f2bu(v0.y); o[2] = f2bu(v0.z); o[3] = f2bu(v0.w);
    o[4] = f2bu(v1.x); o[5] = f2bu(v1.y); o[6] = f2bu(v1.z); o[7] = f2bu(v1.w);
  } else {
    r = *reinterpret_cast<const short8*>((const u16*)p + i);
  }
  return r;
}

// ---------- Kernel A: weight precompute (transposed bf16) + rowptr + flag ----
// Wtn[c][k] (192x64): c<64 -> W_node^T; c<128 -> (W_node@W1)^T; else (W_node@W3)^T
// Wte[c][k] (64x64): (W_edge@W2)^T.
// c1 = b_node@W1 + b_comb  (combine bias FOLDED here -> hs carries it, so
// k_combine needs no bias stage at all).  c3 = b_node@W3.
// rowptr[n] = lower_bound(src, n), n in [0,2000].  flags[0] = f32 dtype flag.
__global__ __launch_bounds__(256) void k_pre(
    const void* __restrict__ x,
    const void* __restrict__ W_edge, const void* __restrict__ W_node,
    const void* __restrict__ b_node, const void* __restrict__ W_comb,
    const void* __restrict__ b_comb,
    const int* __restrict__ src,
    u16* __restrict__ Wtn, u16* __restrict__ Wte,
    float* __restrict__ c1, float* __restrict__ c3,
    int* __restrict__ rowptr, int* __restrict__ flags) {
  const int f32 = detect_f32(x);
  int o = blockIdx.x * 256 + threadIdx.x;
  if (o < 4096) {
    int c = o >> 6, k = o & 63;
    Wtn[c*64 + k] = f2bu(ldin(W_node, k*64 + c, f32));
  } else if (o < 12288) {
    int oo = o - 4096;            // [0, 8192)
    int cc = oo >> 6, k = oo & 63;
    int col = cc & 63;
    int base = (cc < 64) ? 0 : 128;
    float a = 0.f;
    for (int j = 0; j < 64; ++j)
      a += ldin(W_node, k*64 + j, f32) * ldin(W_comb, (base + j)*64 + col, f32);
    Wtn[(64 + cc)*64 + k] = f2bu(a);
  } else if (o < 16384) {
    int oo = o - 12288;
    int c = oo >> 6, k = oo & 63;
    float a = 0.f;
    for (int j = 0; j < 64; ++j)
      a += ldin(W_edge, k*64 + j, f32) * ldin(W_comb, (64 + j)*64 + c, f32);
    Wte[c*64 + k] = f2bu(a);
  } else if (o < 16448) {
    int j = o - 16384;
    float a = ldin(b_comb, j, f32);               // b_comb fold
    for (int k = 0; k < 64; ++k) a += ldin(b_node, k, f32) * ldin(W_comb, k*64 + j, f32);
    c1[j] = a;
  } else if (o < 16512) {
    int j = o - 16448;
    float a = 0.f;
    for (int k = 0; k < 64; ++k) a += ldin(b_node, k, f32) * ldin(W_comb, (128 + k)*64 + j, f32);
    c3[j] = a;
  } else if (o < 16512 + N_ + 1) {
    int n = o - 16512;
    int lo = 0, hi = P_;
    while (lo < hi) { int mid = (lo + hi) >> 1; if (src[mid] < n) lo = mid + 1; else hi = mid; }
    rowptr[n] = lo;
  } else if (o == 16512 + N_ + 1) {
    flags[0] = f32;
  }
}

// ---------- Kernel B: fused node+edge transform, MFMA, LDS-free ----------
// blocks [0,500): node rows, 64/block (4 waves x 16 rows), 12 col-tiles:
//   [h|hs|hd](64x192) = X @ Wn(64x192)
// blocks [500,1500): edge rows, 128/block (4 waves x 32 rows), 4 col-tiles:
//   fe(128x64) = X @ A2
// A-frags straight from global x (coalesced: lanes {m,m+16,m+32,m+48} cover one
// row's 128B half); B-frags from precomputed transposed weights (L1-resident).
__global__ __launch_bounds__(256) void k_transform(
    const void* __restrict__ x, const int* __restrict__ flags,
    const u16* __restrict__ Wtn, const u16* __restrict__ Wte,
    const void* __restrict__ b_node,
    const float* __restrict__ c1, const float* __restrict__ c3,
    bf16* __restrict__ h, bf16* __restrict__ hs, bf16* __restrict__ hd,
    bf16* __restrict__ fe) {
  const int f32 = flags[0];
  int t = threadIdx.x;
  int wave = t >> 6, lane = t & 63;
  int m16 = lane & 15, q = lane >> 4;
  if (blockIdx.x < 500) {
    int row0 = blockIdx.x * 64 + wave * 16;
    int arow = row0 + m16;
    int b = arow / N_, n = arow - b * N_;
    size_t xbase = (size_t)(b * XROW + E_ + n) * 64;
    short8 af0 = ld8b(x, xbase + q*8, f32);
    short8 af1 = ld8b(x, xbase + 32 + q*8, f32);
    f32x4 acc[12];
    #pragma unroll
    for (int c = 0; c < 12; ++c) acc[c] = (f32x4){0.f, 0.f, 0.f, 0.f};
    #pragma unroll
    for (int c = 0; c < 12; ++c) {
      short8 b0 = *reinterpret_cast<const short8*>(&Wtn[(c*16 + m16)*64 + q*8]);
      short8 b1 = *reinterpret_cast<const short8*>(&Wtn[(c*16 + m16)*64 + 32 + q*8]);
      acc[c] = __builtin_amdgcn_mfma_f32_16x16x32_bf16(af0, b0, acc[c], 0, 0, 0);
      acc[c] = __builtin_amdgcn_mfma_f32_16x16x32_bf16(af1, b1, acc[c], 0, 0, 0);
    }
    // D: col = m16 (within tile), row = q*4 + r
    #pragma unroll
    for (int c = 0; c < 12; ++c) {
      int seg = c >> 2;             // 0:h 1:hs 2:hd
      int lcol = (c*16 + m16) & 63;
      float bias = (seg == 0) ? ldin(b_node, lcol, f32) : (seg == 1 ? c1[lcol] : c3[lcol]);
      bf16* tgt = (seg == 0) ? h : (seg == 1 ? hs : hd);
      #pragma unroll
      for (int r = 0; r < 4; ++r) {
        int row = row0 + q*4 + r;
        tgt[(size_t)row*64 + lcol] = __float2bfloat16(acc[c][r] + bias);
      }
    }
  } else {
    int row0 = (blockIdx.x - 500) * 128 + wave * 32;
    short8 af[2][2];
    #pragma unroll
    for (int rt = 0; rt < 2; ++rt) {
      int arow = row0 + rt*16 + m16;
      int b = arow / E_, e = arow - b * E_;
      size_t xbase = (size_t)(b * XROW + e) * 64;
      af[rt][0] = ld8b(x, xbase + q*8, f32);
      af[rt][1] = ld8b(x, xbase + 32 + q*8, f32);
    }
    f32x4 acc[2][4];
    #pragma unroll
    for (int rt = 0; rt < 2; ++rt)
      #pragma unroll
      for (int c = 0; c < 4; ++c) acc[rt][c] = (f32x4){0.f, 0.f, 0.f, 0.f};
    #pragma unroll
    for (int c = 0; c < 4; ++c) {
      short8 b0 = *reinterpret_cast<const short8*>(&Wte[(c*16 + m16)*64 + q*8]);
      short8 b1 = *reinterpret_cast<const short8*>(&Wte[(c*16 + m16)*64 + 32 + q*8]);
      #pragma unroll
      for (int rt = 0; rt < 2; ++rt) {
        acc[rt][c] = __builtin_amdgcn_mfma_f32_16x16x32_bf16(af[rt][0], b0, acc[rt][c], 0, 0, 0);
        acc[rt][c] = __builtin_amdgcn_mfma_f32_16x16x32_bf16(af[rt][1], b1, acc[rt][c], 0, 0, 0);
      }
    }
    #pragma unroll
    for (int rt = 0; rt < 2; ++rt)
      #pragma unroll
      for (int c = 0; c < 4; ++c) {
        int col = c*16 + m16;
        #pragma unroll
        for (int r = 0; r < 4; ++r) {
          int row = row0 + rt*16 + q*4 + r;
          fe[(size_t)row*64 + col] = __float2bfloat16(acc[rt][c][r]);
        }
      }
  }
}

// ---------- Kernel C: gather+combine+lrelu+logit + per-block softmax partial --
// 8 lanes/row x 8 ch (uint4 = 16B gathers), 32 rows/block (all same batch).
// XCD-chunk swizzle (T1): chunk = (bid&7)*1000 + bid>>3. mpart/spart indexed by
// CHUNK (batch b partials = chunks [500b, 500b+500), matching k_smerge).
// R6 slim-down: no bias stage (folded into hs via c1), no head LDS/barrier
// (w_attn read per-lane from global, L1-broadcast), indices loaded first so
// gathers issue at block start, nontemporal out stores (keep L2 for gathers).
__global__ __launch_bounds__(256) void k_combine(
    const int* __restrict__ flags,
    const bf16* __restrict__ hs, const bf16* __restrict__ hd,
    const bf16* __restrict__ fe,
    const void* __restrict__ w_attn,
    const int* __restrict__ src, const int* __restrict__ dst,
    const int* __restrict__ eidx,
    void* __restrict__ out, float* __restrict__ logits,
    float* __restrict__ mpart, float* __restrict__ spart) {
  const int f32 = flags[0];
  __shared__ float ld_log[32];
  int t = threadIdx.x;
  int chunk = (blockIdx.x & 7) * 1000 + (blockIdx.x >> 3);  // bijective, 8000%8==0
  int lane = t & 63, wave = t >> 6;
  int grp = lane >> 3, sub = lane & 7, c0 = sub * 8;
  int r = chunk * 32 + wave * 8 + grp;   // [0, B*P)
  int b = r / P_, p = r - b * P_;
  int s = src[p], d2 = dst[p], e = eidx[p];
  uint4 ua = *reinterpret_cast<const uint4*>((const u16*)hs + (size_t)(b*N_ + s)*64 + c0);
  uint4 uf = *reinterpret_cast<const uint4*>((const u16*)fe + (size_t)(b*E_ + e)*64 + c0);
  uint4 ud = *reinterpret_cast<const uint4*>((const u16*)hd + (size_t)(b*N_ + d2)*64 + c0);
  float w[8];
  if (f32) {
    float4 w0 = *reinterpret_cast<const float4*>((const float*)w_attn + c0);
    float4 w1 = *reinterpret_cast<const float4*>((const float*)w_attn + c0 + 4);
    w[0] = w0.x; w[1] = w0.y; w[2] = w0.z; w[3] = w0.w;
    w[4] = w1.x; w[5] = w1.y; w[6] = w1.z; w[7] = w1.w;
  } else {
    uint4 uw = *reinterpret_cast<const uint4*>((const u16*)w_attn + c0);
    w[0] = lo2f(uw.x); w[1] = hi2f(uw.x);
    w[2] = lo2f(uw.y); w[3] = hi2f(uw.y);
    w[4] = lo2f(uw.z); w[5] = hi2f(uw.z);
    w[6] = lo2f(uw.w); w[7] = hi2f(uw.w);
  }
  float v[8];
  v[0] = lo2f(ua.x) + lo2f(uf.x) + lo2f(ud.x);
  v[1] = hi2f(ua.x) + hi2f(uf.x) + hi2f(ud.x);
  v[2] = lo2f(ua.y) + lo2f(uf.y) + lo2f(ud.y);
  v[3] = hi2f(ua.y) + hi2f(uf.y) + hi2f(ud.y);
  v[4] = lo2f(ua.z) + lo2f(uf.z) + lo2f(ud.z);
  v[5] = hi2f(ua.z) + hi2f(uf.z) + hi2f(ud.z);
  v[6] = lo2f(ua.w) + lo2f(uf.w) + lo2f(ud.w);
  v[7] = hi2f(ua.w) + hi2f(uf.w) + hi2f(ud.w);
  float l = 0.f;
  #pragma unroll
  for (int j = 0; j < 8; ++j) {
    v[j] = v[j] > 0.f ? v[j] : 0.01f * v[j];
    l += v[j] * w[j];
  }
  size_t obase = (size_t)(b*OROW + p)*64 + c0;
  if (f32) {
    f32x4 o0; o0[0] = v[0]; o0[1] = v[1]; o0[2] = v[2]; o0[3] = v[3];
    f32x4 o1; o1[0] = v[4]; o1[1] = v[5]; o1[2] = v[6]; o1[3] = v[7];
    __builtin_nontemporal_store(o0, reinterpret_cast<f32x4*>((float*)out + obase));
    __builtin_nontemporal_store(o1, reinterpret_cast<f32x4*>((float*)out + obase + 4));
  } else {
    u32x4 o;
    o[0] = ((u32)f2bu(v[1]) << 16) | f2bu(v[0]);
    o[1] = ((u32)f2bu(v[3]) << 16) | f2bu(v[2]);
    o[2] = ((u32)f2bu(v[5]) << 16) | f2bu(v[4]);
    o[3] = ((u32)f2bu(v[7]) << 16) | f2bu(v[6]);
    __builtin_nontemporal_store(o, reinterpret_cast<u32x4*>((u16*)out + obase));
  }
  l += __shfl_down(l, 4, 8);
  l += __shfl_down(l, 2, 8);
  l += __shfl_down(l, 1, 8);
  if (sub == 0) {
    logits[b*P_ + p] = l;
    ld_log[wave * 8 + grp] = l;
  }
  __syncthreads();
  if (t < 32) {
    float li = ld_log[t];
    float m = li;
    #pragma unroll
    for (int o = 16; o > 0; o >>= 1) m = fmaxf(m, __shfl_xor(m, o, 32));
    float sv = __expf(li - m);
    #pragma unroll
    for (int o = 16; o > 0; o >>= 1) sv += __shfl_xor(sv, o, 32);
    if (t == 0) { mpart[chunk] = m; spart[chunk] = sv; }
  }
}

// ---------- Kernel C2: merge 500 partials per batch -> (M, 1/S) ----------
__global__ __launch_bounds__(256) void k_smerge(
    const float* __restrict__ mpart, const float* __restrict__ spart,
    float* __restrict__ mb, float* __restrict__ sb) {
  __shared__ float rm[256], rs[256];
  int b = blockIdx.x, t = threadIdx.x;
  float m = -1e30f, s = 0.f;
  for (int j = t; j < 500; j += 256) {
    float mj = mpart[500*b + j], sj = spart[500*b + j];
    float nm = fmaxf(m, mj);
    s = s * __expf(m - nm) + sj * __expf(mj - nm);
    m = nm;
  }
  rm[t] = m; rs[t] = s; __syncthreads();
  for (int st = 128; st > 0; st >>= 1) {
    if (t < st) {
      float mo = rm[t + st], so = rs[t + st];
      float nm = fmaxf(rm[t], mo);
      rs[t] = rs[t] * __expf(rm[t] - nm) + so * __expf(mo - nm);
      rm[t] = nm;
    }
    __syncthreads();
  }
  if (t == 0) { mb[b] = rm[0]; sb[b] = 1.0f / rs[0]; }
}

// ---------- Kernel D: h_out ----------
// grid (N_, 4), block 256 = 4 waves (one batch each). rowptr gives the node's
// edge range; 4 edge-groups x 16 ch gather-dot; xor-reduce across groups.
// Nontemporal out stores (out is write-only for us).
__global__ __launch_bounds__(256) void k_hout(
    const int* __restrict__ flags,
    const bf16* __restrict__ h, const float* __restrict__ logits,
    const float* __restrict__ mb, const float* __restrict__ sb,
    const int* __restrict__ rowptr, const int* __restrict__ dst,
    void* __restrict__ out) {
  const int f32 = flags[0];
  int n = blockIdx.x;
  int t = threadIdx.x;
  int wave = t >> 6, lane = t & 63;
  int b = blockIdx.y * 4 + wave;
  float m = mb[b], inv = sb[b];
  int start = rowptr[n], end = rowptr[n + 1];
  int grp = lane >> 4, sub = lane & 15, c0 = sub * 4;
  float a0 = 0.f, a1 = 0.f, a2 = 0.f, a3 = 0.f;
  for (int p = start + grp; p < end; p += 4) {
    float a = __expf(logits[b*P_ + p] - m) * inv;
    int dn = dst[p];
    ushort4 hv = *reinterpret_cast<const ushort4*>((const u16*)h + (size_t)(b*N_ + dn)*64 + c0);
    a0 += a * u2f(hv.x); a1 += a * u2f(hv.y);
    a2 += a * u2f(hv.z); a3 += a * u2f(hv.w);
  }
  a0 += __shfl_xor(a0, 16, 64); a0 += __shfl_xor(a0, 32, 64);
  a1 += __shfl_xor(a1, 16, 64); a1 += __shfl_xor(a1, 32, 64);
  a2 += __shfl_xor(a2, 16, 64); a2 += __shfl_xor(a2, 32, 64);
  a3 += __shfl_xor(a3, 16, 64); a3 += __shfl_xor(a3, 32, 64);
  if (grp == 0) {
    size_t obase = (size_t)(b*OROW + P_ + n)*64 + c0;
    if (f32) {
      f32x4 o4; o4[0] = a0; o4[1] = a1; o4[2] = a2; o4[3] = a3;
      __builtin_nontemporal_store(o4, reinterpret_cast<f32x4*>((float*)out + obase));
    } else {
      u16x4 o4;
      o4[0] = f2bu(a0); o4[1] = f2bu(a1); o4[2] = f2bu(a2); o4[3] = f2bu(a3);
      __builtin_nontemporal_store(o4, reinterpret_cast<u16x4*>((u16*)out + obase));
    }
  }
}

extern "C" void kernel_launch(void* const* d_in, const int* in_sizes, int n_in,
                              void* d_out, int out_size, void* d_ws, size_t ws_size,
                              hipStream_t stream) {
  const void* x      = d_in[0];
  const void* W_edge = d_in[1];
  const void* W_node = d_in[2];
  const void* b_node = d_in[3];
  const void* W_comb = d_in[4];
  const void* b_comb = d_in[5];
  const void* w_attn = d_in[6];
  const int* src  = (const int*)d_in[7];
  const int* dst  = (const int*)d_in[8];
  const int* eidx = (const int*)d_in[9];

  // workspace layout (f32 units)
  float* logits = (float*)d_ws;          // 256000
  float* mpart  = logits + B_*P_;        // 8000
  float* spart  = mpart + 8000;          // 8000
  float* mb     = spart + 8000;          // 16
  float* sb     = mb + B_;               // 16
  float* c1     = sb + B_;               // 64
  float* c3     = c1 + 64;               // 64
  int*   rowptr = (int*)(c3 + 64);       // 2016 (padded)
  int*   flags  = rowptr + 2016;         // 16 (dtype flag, padded)
  u16*   Wtn    = (u16*)(flags + 16);    // 192*64
  u16*   Wte    = Wtn + 192*64;          // 64*64
  bf16*  h      = (bf16*)(Wte + 64*64);  // B*N*64
  bf16*  hs     = h  + B_*N_*64;
  bf16*  hd     = hs + B_*N_*64;
  bf16*  fe     = hd + B_*N_*64;         // B*E*64

  k_pre<<<73, 256, 0, stream>>>(x, W_edge, W_node, b_node, W_comb, b_comb, src, Wtn, Wte, c1, c3, rowptr, flags);
  k_transform<<<1500, 256, 0, stream>>>(x, flags, Wtn, Wte, b_node, c1, c3, h, hs, hd, fe);
  k_combine<<<(B_*P_)/32, 256, 0, stream>>>(flags, hs, hd, fe, w_attn, src, dst, eidx, d_out, logits, mpart, spart);
  k_smerge<<<B_, 256, 0, stream>>>(mpart, spart, mb, sb);
  k_hout<<<dim3(N_, B_/4), 256, 0, stream>>>(flags, h, logits, mb, sb, rowptr, dst, d_out);
}